// Round 2
// baseline (649.564 us; speedup 1.0000x reference)
//
#include <hip/hip_runtime.h>

// Grouped GRU, G=8, H=I=64. 2 chains per 512-thread block (grid = G*B/2 = 128).
// Per chain: 256 threads; thread (j = ct>>2, p = ct&3) owns hidden row j, k-quarter p.
// Weights (6 row-slices x 16 floats) pinned in VGPRs via no-op asm (defeats remat).
// x_t and h broadcast via LDS; DPP quad reduction; 1 barrier/step.
// x streamed via 8-step chunked register prefetch (load ph0, ds_write ph7, dbuf).
// 2 independent chains per SIMD hide each other's dependency stalls.

#define TPB 512
#define CPB 2   // chains per block

__device__ __forceinline__ float fast_rcp(float v) { return __builtin_amdgcn_rcpf(v); }
__device__ __forceinline__ float sigm(float v)     { return fast_rcp(1.f + __expf(-v)); }
__device__ __forceinline__ float tanh_f(float v)   { return 1.f - 2.f * fast_rcp(1.f + __expf(2.f * v)); }

__device__ __forceinline__ float4 fma4(float4 a, float4 b, float4 c) {
    c.x = __builtin_fmaf(a.x, b.x, c.x);
    c.y = __builtin_fmaf(a.y, b.y, c.y);
    c.z = __builtin_fmaf(a.z, b.z, c.z);
    c.w = __builtin_fmaf(a.w, b.w, c.w);
    return c;
}

// sum across lane quads {4k..4k+3} via DPP (quad_perm swaps): pure VALU, no LDS pipe.
__device__ __forceinline__ float qsum4(float v) {
    int a = __builtin_amdgcn_mov_dpp(__float_as_int(v), 0xB1, 0xF, 0xF, true); // [1,0,3,2]
    v += __int_as_float(a);
    int b = __builtin_amdgcn_mov_dpp(__float_as_int(v), 0x4E, 0xF, 0xF, true); // [2,3,0,1]
    v += __int_as_float(b);
    return v;
}

// No-op pin: makes the value opaque so the compiler can NOT rematerialize the
// originating global load inside the loop; it must keep the value in a VGPR.
#define PIN4(v) asm volatile("" : "+v"((v).x), "+v"((v).y), "+v"((v).z), "+v"((v).w))

__global__ __launch_bounds__(TPB)
void gru_fused(const float* __restrict__ x, const float* __restrict__ h0,
               const float* __restrict__ Wih, const float* __restrict__ Whh,
               const float* __restrict__ bih, const float* __restrict__ bhh,
               float* __restrict__ out, float* __restrict__ hout,
               int B, int T)
{
    const int tid = threadIdx.x;
    const int cl  = tid >> 8;           // chain-local id 0..1
    const int ct  = tid & 255;          // thread within chain
    const int bid = blockIdx.x * CPB + cl;
    const int g   = bid & 7;
    const int b   = bid >> 3;
    const int j   = ct >> 2;            // hidden row 0..63
    const int p   = ct & 3;             // k-quarter 0..3

    // x chunk staging: 8 timesteps * 64 feats = 512 floats; 2 floats/thread
    const int e0  = ct * 2;
    const int phx = e0 >> 6;            // timestep-within-chunk this thread stages
    const int ix  = e0 & 63;            // feature index

    __shared__ float xsc[CPB][2][512];
    __shared__ float hs[CPB][2][64];

    const size_t gw = (size_t)g * 192 * 64;
    const float* WhG = Whh + gw;
    const float* WiG = Wih + gw;
    float4 whr[4], whz[4], whn[4], wxr[4], wxz[4], wxn[4];
#pragma unroll
    for (int i = 0; i < 4; ++i) {
        const int col = p * 16 + i * 4;
        whr[i] = *(const float4*)(WhG + (j      ) * 64 + col);
        whz[i] = *(const float4*)(WhG + (j +  64) * 64 + col);
        whn[i] = *(const float4*)(WhG + (j + 128) * 64 + col);
        wxr[i] = *(const float4*)(WiG + (j      ) * 64 + col);
        wxz[i] = *(const float4*)(WiG + (j +  64) * 64 + col);
        wxn[i] = *(const float4*)(WiG + (j + 128) * 64 + col);
    }
#pragma unroll
    for (int i = 0; i < 4; ++i) {
        PIN4(whr[i]); PIN4(whz[i]); PIN4(whn[i]);
        PIN4(wxr[i]); PIN4(wxz[i]); PIN4(wxn[i]);
    }

    const float* bihG = bih + g * 192;
    const float* bhhG = bhh + g * 192;
    float b_r  = bihG[j]      + bhhG[j];
    float b_z  = bihG[64 + j] + bhhG[64 + j];
    float bi_n = bihG[128 + j];
    float bh_n = bhhG[128 + j];   // r multiplies (gh_n + bhh_n) only
    asm volatile("" : "+v"(b_r), "+v"(b_z), "+v"(bi_n), "+v"(bh_n));

    float h_reg = h0[((size_t)g * B + b) * 64 + j];
    if (p == 0) hs[cl][0][j] = h_reg;

    const float* xb = x + (size_t)b * T * 512 + (size_t)g * 64;

    // stage chunk 0 (timesteps 0..7)
    float2 cnext = make_float2(0.f, 0.f);
    {
        float2 c0 = make_float2(0.f, 0.f);
        if (phx < T) c0 = *(const float2*)(xb + (size_t)phx * 512 + ix);
        *(float2*)&xsc[cl][0][e0] = c0;
    }
    asm volatile("s_waitcnt lgkmcnt(0)" ::: "memory");
    __builtin_amdgcn_s_barrier();
    asm volatile("" ::: "memory");

    float* outp = out + (size_t)b * T * 512 + (size_t)g * 64 + j;

    for (int t8 = 0; t8 < T; t8 += 8) {
        const int bufi = (t8 >> 3) & 1;
        const float* xcb = &xsc[cl][bufi][0];
#pragma unroll
        for (int ph = 0; ph < 8; ++ph) {
            const int t = t8 + ph;
            if (t >= T) break;   // uniform

            // issue next-chunk global loads at phase 0 (in flight ~7 steps)
            if (ph == 0 && t8 + 8 < T)
                cnext = *(const float2*)(xb + (size_t)(t8 + 8 + phx) * 512 + ix);

            const float* hp = &hs[cl][ph & 1][p * 16];
            const float* xp = xcb + ph * 64 + p * 16;

            float4 ar  = make_float4(0.f, 0.f, 0.f, 0.f);
            float4 az  = make_float4(0.f, 0.f, 0.f, 0.f);
            float4 axn = make_float4(0.f, 0.f, 0.f, 0.f);
            float4 ahn = make_float4(0.f, 0.f, 0.f, 0.f);
#pragma unroll
            for (int i = 0; i < 4; ++i) {
                const float4 hv = *(const float4*)(hp + i * 4);
                const float4 xv = *(const float4*)(xp + i * 4);
                ar  = fma4(whr[i], hv, ar);
                az  = fma4(whz[i], hv, az);
                ahn = fma4(whn[i], hv, ahn);
                ar  = fma4(wxr[i], xv, ar);
                az  = fma4(wxz[i], xv, az);
                axn = fma4(wxn[i], xv, axn);
            }
            float sr  = (ar.x  + ar.y ) + (ar.z  + ar.w );
            float sz  = (az.x  + az.y ) + (az.z  + az.w );
            float sxn = (axn.x + axn.y) + (axn.z + axn.w);
            float shn = (ahn.x + ahn.y) + (ahn.z + ahn.w);
            sr = qsum4(sr); sz = qsum4(sz); sxn = qsum4(sxn); shn = qsum4(shn);

            const float r  = sigm(sr + b_r);
            const float zg = sigm(sz + b_z);
            const float nv = tanh_f(sxn + bi_n + r * (shn + bh_n));
            h_reg = nv + zg * (h_reg - nv);   // (1-z)*n + z*h

            if (p == 0) hs[cl][(ph & 1) ^ 1][j] = h_reg;   // next-step h (dbuf)
            if (p == 1) outp[(size_t)t * 512] = h_reg;     // output row t

            // ds_write next-chunk x at phase 7 (compiler inserts vmcnt wait on cnext)
            if (ph == 7 && t8 + 8 < T)
                *(float2*)&xsc[cl][bufi ^ 1][e0] = cnext;

            asm volatile("s_waitcnt lgkmcnt(0)" ::: "memory");
            __builtin_amdgcn_s_barrier();
            asm volatile("" ::: "memory");
        }
    }

    if (p == 0) hout[((size_t)g * B + b) * 64 + j] = h_reg;   // h_final [G,B,H]
}

extern "C" void kernel_launch(void* const* d_in, const int* in_sizes, int n_in,
                              void* d_out, int out_size, void* d_ws, size_t ws_size,
                              hipStream_t stream) {
    (void)n_in; (void)d_ws; (void)ws_size; (void)out_size;
    const float* x   = (const float*)d_in[0];
    const float* h0  = (const float*)d_in[1];
    const float* Wih = (const float*)d_in[2];
    const float* Whh = (const float*)d_in[3];
    const float* bih = (const float*)d_in[4];
    const float* bhh = (const float*)d_in[5];

    const int B = in_sizes[1] / 512;                 // h0 = G*B*H = 8*B*64
    const int T = (int)((long long)in_sizes[0] / ((long long)B * 512)); // x = B*T*512

    float* out  = (float*)d_out;
    float* hout = out + (size_t)B * T * 512;

    dim3 grid((B * 8) / CPB), block(TPB);
    hipLaunchKernelGGL(gru_fused, grid, block, 0, stream,
                       x, h0, Wih, Whh, bih, bhh, out, hout, B, T);
}

// Round 3
// 648.297 us; speedup vs baseline: 1.0020x; 1.0020x over previous
//
#include <hip/hip_runtime.h>

// Grouped GRU, G=8, H=I=64. 2 chains per 512-thread block (grid = G*B/2 = 128).
// Per chain: 256 threads; thread (j = ct>>2, p = ct&3) owns hidden row j, k-quarter p.
// Weights (6 row-slices x 16 floats) pinned in VGPRs via no-op asm (defeats remat),
// and amdgpu_waves_per_eu(2,2) gives the allocator a 256-VGPR budget so the pins
// STAY in registers (R2 lesson: without it, scheduler targets 8 waves/EU and
// spills the pins to scratch).
// x_t and h broadcast via LDS; DPP quad reduction; 1 barrier/step.
// x streamed via 8-step chunked register prefetch (load ph0, ds_write ph7, dbuf).

#define TPB 512
#define CPB 2   // chains per block

__device__ __forceinline__ float fast_rcp(float v) { return __builtin_amdgcn_rcpf(v); }
__device__ __forceinline__ float sigm(float v)     { return fast_rcp(1.f + __expf(-v)); }
__device__ __forceinline__ float tanh_f(float v)   { return 1.f - 2.f * fast_rcp(1.f + __expf(2.f * v)); }

__device__ __forceinline__ float4 fma4(float4 a, float4 b, float4 c) {
    c.x = __builtin_fmaf(a.x, b.x, c.x);
    c.y = __builtin_fmaf(a.y, b.y, c.y);
    c.z = __builtin_fmaf(a.z, b.z, c.z);
    c.w = __builtin_fmaf(a.w, b.w, c.w);
    return c;
}

// sum across lane quads {4k..4k+3} via DPP (quad_perm swaps): pure VALU, no LDS pipe.
__device__ __forceinline__ float qsum4(float v) {
    int a = __builtin_amdgcn_mov_dpp(__float_as_int(v), 0xB1, 0xF, 0xF, true); // [1,0,3,2]
    v += __int_as_float(a);
    int b = __builtin_amdgcn_mov_dpp(__float_as_int(v), 0x4E, 0xF, 0xF, true); // [2,3,0,1]
    v += __int_as_float(b);
    return v;
}

// No-op pin: makes the value opaque so the compiler can NOT rematerialize the
// originating global load inside the loop; it must keep the value in a VGPR.
#define PIN4(v) asm volatile("" : "+v"((v).x), "+v"((v).y), "+v"((v).z), "+v"((v).w))

__global__ __launch_bounds__(TPB)
__attribute__((amdgpu_waves_per_eu(2, 2)))
void gru_fused(const float* __restrict__ x, const float* __restrict__ h0,
               const float* __restrict__ Wih, const float* __restrict__ Whh,
               const float* __restrict__ bih, const float* __restrict__ bhh,
               float* __restrict__ out, float* __restrict__ hout,
               int B, int T)
{
    const int tid = threadIdx.x;
    const int cl  = tid >> 8;           // chain-local id 0..1
    const int ct  = tid & 255;          // thread within chain
    const int bid = blockIdx.x * CPB + cl;
    const int g   = bid & 7;
    const int b   = bid >> 3;
    const int j   = ct >> 2;            // hidden row 0..63
    const int p   = ct & 3;             // k-quarter 0..3

    // x chunk staging: 8 timesteps * 64 feats = 512 floats; 2 floats/thread
    const int e0  = ct * 2;
    const int phx = e0 >> 6;            // timestep-within-chunk this thread stages
    const int ix  = e0 & 63;            // feature index

    __shared__ float xsc[CPB][2][512];
    __shared__ float hs[CPB][2][64];

    const size_t gw = (size_t)g * 192 * 64;
    const float* WhG = Whh + gw;
    const float* WiG = Wih + gw;
    float4 whr[4], whz[4], whn[4], wxr[4], wxz[4], wxn[4];
#pragma unroll
    for (int i = 0; i < 4; ++i) {
        const int col = p * 16 + i * 4;
        whr[i] = *(const float4*)(WhG + (j      ) * 64 + col);
        whz[i] = *(const float4*)(WhG + (j +  64) * 64 + col);
        whn[i] = *(const float4*)(WhG + (j + 128) * 64 + col);
        wxr[i] = *(const float4*)(WiG + (j      ) * 64 + col);
        wxz[i] = *(const float4*)(WiG + (j +  64) * 64 + col);
        wxn[i] = *(const float4*)(WiG + (j + 128) * 64 + col);
    }
#pragma unroll
    for (int i = 0; i < 4; ++i) {
        PIN4(whr[i]); PIN4(whz[i]); PIN4(whn[i]);
        PIN4(wxr[i]); PIN4(wxz[i]); PIN4(wxn[i]);
    }

    const float* bihG = bih + g * 192;
    const float* bhhG = bhh + g * 192;
    float b_r  = bihG[j]      + bhhG[j];
    float b_z  = bihG[64 + j] + bhhG[64 + j];
    float bi_n = bihG[128 + j];
    float bh_n = bhhG[128 + j];   // r multiplies (gh_n + bhh_n) only
    asm volatile("" : "+v"(b_r), "+v"(b_z), "+v"(bi_n), "+v"(bh_n));

    float h_reg = h0[((size_t)g * B + b) * 64 + j];
    if (p == 0) hs[cl][0][j] = h_reg;

    const float* xb = x + (size_t)b * T * 512 + (size_t)g * 64;

    // stage chunk 0 (timesteps 0..7)
    float2 cnext = make_float2(0.f, 0.f);
    {
        float2 c0 = make_float2(0.f, 0.f);
        if (phx < T) c0 = *(const float2*)(xb + (size_t)phx * 512 + ix);
        *(float2*)&xsc[cl][0][e0] = c0;
    }
    asm volatile("s_waitcnt lgkmcnt(0)" ::: "memory");
    __builtin_amdgcn_s_barrier();
    asm volatile("" ::: "memory");

    float* outp = out + (size_t)b * T * 512 + (size_t)g * 64 + j;

    for (int t8 = 0; t8 < T; t8 += 8) {
        const int bufi = (t8 >> 3) & 1;
        const float* xcb = &xsc[cl][bufi][0];
#pragma unroll
        for (int ph = 0; ph < 8; ++ph) {
            const int t = t8 + ph;
            if (t >= T) break;   // uniform

            // issue next-chunk global loads at phase 0 (in flight ~7 steps)
            if (ph == 0 && t8 + 8 < T)
                cnext = *(const float2*)(xb + (size_t)(t8 + 8 + phx) * 512 + ix);

            const float* hp = &hs[cl][ph & 1][p * 16];
            const float* xp = xcb + ph * 64 + p * 16;

            float4 ar  = make_float4(0.f, 0.f, 0.f, 0.f);
            float4 az  = make_float4(0.f, 0.f, 0.f, 0.f);
            float4 axn = make_float4(0.f, 0.f, 0.f, 0.f);
            float4 ahn = make_float4(0.f, 0.f, 0.f, 0.f);
#pragma unroll
            for (int i = 0; i < 4; ++i) {
                const float4 hv = *(const float4*)(hp + i * 4);
                const float4 xv = *(const float4*)(xp + i * 4);
                ar  = fma4(whr[i], hv, ar);
                az  = fma4(whz[i], hv, az);
                ahn = fma4(whn[i], hv, ahn);
                ar  = fma4(wxr[i], xv, ar);
                az  = fma4(wxz[i], xv, az);
                axn = fma4(wxn[i], xv, axn);
            }
            float sr  = (ar.x  + ar.y ) + (ar.z  + ar.w );
            float sz  = (az.x  + az.y ) + (az.z  + az.w );
            float sxn = (axn.x + axn.y) + (axn.z + axn.w);
            float shn = (ahn.x + ahn.y) + (ahn.z + ahn.w);
            sr = qsum4(sr); sz = qsum4(sz); sxn = qsum4(sxn); shn = qsum4(shn);

            const float r  = sigm(sr + b_r);
            const float zg = sigm(sz + b_z);
            const float nv = tanh_f(sxn + bi_n + r * (shn + bh_n));
            h_reg = nv + zg * (h_reg - nv);   // (1-z)*n + z*h

            if (p == 0) hs[cl][(ph & 1) ^ 1][j] = h_reg;   // next-step h (dbuf)
            if (p == 1) outp[(size_t)t * 512] = h_reg;     // output row t

            // ds_write next-chunk x at phase 7 (compiler inserts vmcnt wait on cnext)
            if (ph == 7 && t8 + 8 < T)
                *(float2*)&xsc[cl][bufi ^ 1][e0] = cnext;

            asm volatile("s_waitcnt lgkmcnt(0)" ::: "memory");
            __builtin_amdgcn_s_barrier();
            asm volatile("" ::: "memory");
        }
    }

    if (p == 0) hout[((size_t)g * B + b) * 64 + j] = h_reg;   // h_final [G,B,H]
}

extern "C" void kernel_launch(void* const* d_in, const int* in_sizes, int n_in,
                              void* d_out, int out_size, void* d_ws, size_t ws_size,
                              hipStream_t stream) {
    (void)n_in; (void)d_ws; (void)ws_size; (void)out_size;
    const float* x   = (const float*)d_in[0];
    const float* h0  = (const float*)d_in[1];
    const float* Wih = (const float*)d_in[2];
    const float* Whh = (const float*)d_in[3];
    const float* bih = (const float*)d_in[4];
    const float* bhh = (const float*)d_in[5];

    const int B = in_sizes[1] / 512;                 // h0 = G*B*H = 8*B*64
    const int T = (int)((long long)in_sizes[0] / ((long long)B * 512)); // x = B*T*512

    float* out  = (float*)d_out;
    float* hout = out + (size_t)B * T * 512;

    dim3 grid((B * 8) / CPB), block(TPB);
    hipLaunchKernelGGL(gru_fused, grid, block, 0, stream,
                       x, h0, Wih, Whh, bih, bhh, out, hout, B, T);
}

// Round 4
// 587.187 us; speedup vs baseline: 1.1062x; 1.1041x over previous
//
#include <hip/hip_runtime.h>

// Grouped GRU, G=8, H=I=64. ONE chain per 512-thread block (grid = G*B = 256).
// Thread (j = tid>>3, p = tid&7): owns hidden row j, k-EIGHTH p (8 floats/dot).
// R1-R3 lesson: compiler's remat/spill heuristic refuses ~96 resident weight
// VGPRs regardless of budget (settles at 72-88). So shrink per-thread weights
// to 12 float4 = 48 VGPRs (total ~95 live) -> fits the allocator's comfort zone.
// Within a step, all 8 waves are independent between barriers -> 2 waves/SIMD
// hide each other's LDS/transcendental latency.
// Reduction over 8 p-lanes: xor1/xor2 DPP quad_perm (VALU pipe), xor4 ds_swizzle.
// x streamed via 16-step chunked register prefetch (load ph0, ds_write ph14, dbuf).

#define TPB 512
#define CH  16   // timesteps per staged x chunk

__device__ __forceinline__ float fast_rcp(float v) { return __builtin_amdgcn_rcpf(v); }
__device__ __forceinline__ float sigm(float v)     { return fast_rcp(1.f + __expf(-v)); }
__device__ __forceinline__ float tanh_f(float v)   { return 1.f - 2.f * fast_rcp(1.f + __expf(2.f * v)); }

__device__ __forceinline__ float4 mul4(float4 a, float4 b) {
    return make_float4(a.x * b.x, a.y * b.y, a.z * b.z, a.w * b.w);
}
__device__ __forceinline__ float4 fma4(float4 a, float4 b, float4 c) {
    c.x = __builtin_fmaf(a.x, b.x, c.x);
    c.y = __builtin_fmaf(a.y, b.y, c.y);
    c.z = __builtin_fmaf(a.z, b.z, c.z);
    c.w = __builtin_fmaf(a.w, b.w, c.w);
    return c;
}
__device__ __forceinline__ float hadd4(float4 a) { return (a.x + a.y) + (a.z + a.w); }

// sum across the 8 p-lanes (lane bits 0..2): xor1,xor2 via DPP; xor4 via ds_swizzle.
__device__ __forceinline__ float psum8(float v) {
    int a = __builtin_amdgcn_mov_dpp(__float_as_int(v), 0xB1, 0xF, 0xF, true); // quad_perm [1,0,3,2]
    v += __int_as_float(a);
    a = __builtin_amdgcn_mov_dpp(__float_as_int(v), 0x4E, 0xF, 0xF, true);     // quad_perm [2,3,0,1]
    v += __int_as_float(a);
    a = __builtin_amdgcn_ds_swizzle(__float_as_int(v), 0x101F);                // xor 4 (BitMode)
    v += __int_as_float(a);
    return v;
}

#define PIN4(v) asm volatile("" : "+v"((v).x), "+v"((v).y), "+v"((v).z), "+v"((v).w))

__global__ __launch_bounds__(TPB)
__attribute__((amdgpu_waves_per_eu(2, 2)))
void gru_fused(const float* __restrict__ x, const float* __restrict__ h0,
               const float* __restrict__ Wih, const float* __restrict__ Whh,
               const float* __restrict__ bih, const float* __restrict__ bhh,
               float* __restrict__ out, float* __restrict__ hout,
               int B, int T)
{
    const int tid = threadIdx.x;
    const int bid = blockIdx.x;
    const int g   = bid & 7;
    const int b   = bid >> 3;
    const int j   = tid >> 3;   // hidden row 0..63
    const int p   = tid & 7;    // k-eighth 0..7

    // x chunk staging: CH timesteps * 64 feats = 1024 floats; 2 floats/thread
    const int e0  = tid * 2;
    const int phx = e0 >> 6;    // timestep-within-chunk this thread stages (0..15)
    const int ix  = e0 & 63;    // feature index

    __shared__ float xsc[2][CH * 64];
    __shared__ float hs[2][64];

    const size_t gw = (size_t)g * 192 * 64;
    const float* WhG = Whh + gw;
    const float* WiG = Wih + gw;
    const int col = p * 8;
    float4 whr0, whr1, whz0, whz1, whn0, whn1, wxr0, wxr1, wxz0, wxz1, wxn0, wxn1;
    whr0 = *(const float4*)(WhG + (j      ) * 64 + col);
    whr1 = *(const float4*)(WhG + (j      ) * 64 + col + 4);
    whz0 = *(const float4*)(WhG + (j +  64) * 64 + col);
    whz1 = *(const float4*)(WhG + (j +  64) * 64 + col + 4);
    whn0 = *(const float4*)(WhG + (j + 128) * 64 + col);
    whn1 = *(const float4*)(WhG + (j + 128) * 64 + col + 4);
    wxr0 = *(const float4*)(WiG + (j      ) * 64 + col);
    wxr1 = *(const float4*)(WiG + (j      ) * 64 + col + 4);
    wxz0 = *(const float4*)(WiG + (j +  64) * 64 + col);
    wxz1 = *(const float4*)(WiG + (j +  64) * 64 + col + 4);
    wxn0 = *(const float4*)(WiG + (j + 128) * 64 + col);
    wxn1 = *(const float4*)(WiG + (j + 128) * 64 + col + 4);
    PIN4(whr0); PIN4(whr1); PIN4(whz0); PIN4(whz1); PIN4(whn0); PIN4(whn1);
    PIN4(wxr0); PIN4(wxr1); PIN4(wxz0); PIN4(wxz1); PIN4(wxn0); PIN4(wxn1);

    const float* bihG = bih + g * 192;
    const float* bhhG = bhh + g * 192;
    float b_r  = bihG[j]      + bhhG[j];
    float b_z  = bihG[64 + j] + bhhG[64 + j];
    float bi_n = bihG[128 + j];
    float bh_n = bhhG[128 + j];   // r multiplies (gh_n + bhh_n) only
    asm volatile("" : "+v"(b_r), "+v"(b_z), "+v"(bi_n), "+v"(bh_n));

    float h_reg = h0[((size_t)g * B + b) * 64 + j];
    if (p == 0) hs[0][j] = h_reg;

    const float* xb = x + (size_t)b * T * 512 + (size_t)g * 64;

    // stage chunk 0 (timesteps 0..CH-1)
    float2 cnext = make_float2(0.f, 0.f);
    {
        float2 c0 = make_float2(0.f, 0.f);
        if (phx < T) c0 = *(const float2*)(xb + (size_t)phx * 512 + ix);
        *(float2*)&xsc[0][e0] = c0;
    }
    asm volatile("s_waitcnt lgkmcnt(0)" ::: "memory");
    __builtin_amdgcn_s_barrier();
    asm volatile("" ::: "memory");

    float* outp = out + (size_t)b * T * 512 + (size_t)g * 64 + j;

    for (int t16 = 0; t16 < T; t16 += CH) {
        const int bufi = (t16 / CH) & 1;
        const float* xcb = &xsc[bufi][0];
#pragma unroll
        for (int ph = 0; ph < CH; ++ph) {
            const int t = t16 + ph;
            if (t >= T) break;   // uniform

            // issue next-chunk global loads at phase 0 (in flight ~14 steps)
            if (ph == 0 && t16 + CH < T) {
                const int tt = t16 + CH + phx;
                cnext = (tt < T) ? *(const float2*)(xb + (size_t)tt * 512 + ix)
                                 : make_float2(0.f, 0.f);
            }

            const float* hp = &hs[ph & 1][col];
            const float* xp = xcb + ph * 64 + col;

            const float4 h0v = *(const float4*)(hp);
            const float4 h1v = *(const float4*)(hp + 4);
            const float4 x0v = *(const float4*)(xp);
            const float4 x1v = *(const float4*)(xp + 4);

            float4 ar  = mul4(whr0, h0v);  ar  = fma4(whr1, h1v, ar);
            ar  = fma4(wxr0, x0v, ar);     ar  = fma4(wxr1, x1v, ar);
            float4 az  = mul4(whz0, h0v);  az  = fma4(whz1, h1v, az);
            az  = fma4(wxz0, x0v, az);     az  = fma4(wxz1, x1v, az);
            float4 ahn = mul4(whn0, h0v);  ahn = fma4(whn1, h1v, ahn);
            float4 axn = mul4(wxn0, x0v);  axn = fma4(wxn1, x1v, axn);

            float sr  = psum8(hadd4(ar));
            float sz  = psum8(hadd4(az));
            float sxn = psum8(hadd4(axn));
            float shn = psum8(hadd4(ahn));

            const float r  = sigm(sr + b_r);
            const float zg = sigm(sz + b_z);
            const float nv = tanh_f(sxn + bi_n + r * (shn + bh_n));
            h_reg = nv + zg * (h_reg - nv);   // (1-z)*n + z*h

            if (p == 0) hs[(ph & 1) ^ 1][j] = h_reg;   // next-step h (dbuf)
            if (p == 1) outp[(size_t)t * 512] = h_reg; // output row t

            // ds_write next-chunk x near chunk end (vmcnt wait handled by compiler)
            if (ph == CH - 2 && t16 + CH < T)
                *(float2*)&xsc[bufi ^ 1][e0] = cnext;

            asm volatile("s_waitcnt lgkmcnt(0)" ::: "memory");
            __builtin_amdgcn_s_barrier();
            asm volatile("" ::: "memory");
        }
    }

    if (p == 0) hout[((size_t)g * B + b) * 64 + j] = h_reg;   // h_final [G,B,H]
}

extern "C" void kernel_launch(void* const* d_in, const int* in_sizes, int n_in,
                              void* d_out, int out_size, void* d_ws, size_t ws_size,
                              hipStream_t stream) {
    (void)n_in; (void)d_ws; (void)ws_size; (void)out_size;
    const float* x   = (const float*)d_in[0];
    const float* h0  = (const float*)d_in[1];
    const float* Wih = (const float*)d_in[2];
    const float* Whh = (const float*)d_in[3];
    const float* bih = (const float*)d_in[4];
    const float* bhh = (const float*)d_in[5];

    const int B = in_sizes[1] / 512;                 // h0 = G*B*H = 8*B*64
    const int T = (int)((long long)in_sizes[0] / ((long long)B * 512)); // x = B*T*512

    float* out  = (float*)d_out;
    float* hout = out + (size_t)B * T * 512;

    dim3 grid(B * 8), block(TPB);
    hipLaunchKernelGGL(gru_fused, grid, block, 0, stream,
                       x, h0, Wih, Whh, bih, bhh, out, hout, B, T);
}